// Round 7
// baseline (236.265 us; speedup 1.0000x reference)
//
#include <hip/hip_runtime.h>
#include <math.h>

// Problem constants (match reference)
#define ALPHA     1.0f
#define BETA      0.001f
#define GAMMA     0.1f
#define THRESH    0.5f
#define LOG_CLAMP -100.0f
#define LN2       0.69314718055994530942f

constexpr int B = 256, C = 2, H = 192, W = 256;
constexpr int HW   = H * W;          // 49152
constexpr int HW4  = HW / 4;         // 12288 float4 per (b,c) slab
constexpr long long NTOT = (long long)B * C * H * W;  // 25165824
constexpr int N4   = (int)(NTOT / 4);                  // 6291456

constexpr int BCE_BLOCKS   = 2048;   // 8 blocks/CU exact fill
constexpr int PAIRS        = 12;     // 2048*256*12 == N4 exactly
constexpr int NCOL         = B * W;  // 65536 (b,w) columns
constexpr int MERGE_BLOCKS = 256;

// Native Clang vector type — __builtin_nontemporal_load rejects HIP's float4.
typedef float vfloat4 __attribute__((ext_vector_type(4)));

// Hardware v_log_f32 (log2) * ln2, ~1 ulp — threshold is 6.7e3 absolute.
__device__ __forceinline__ float fast_log(float x) {
    return fmaxf(__builtin_amdgcn_logf(x) * LN2, LOG_CLAMP);
}

__device__ __forceinline__ vfloat4 nt_load4(const vfloat4* p) {
    return __builtin_nontemporal_load(p);
}

__device__ __forceinline__ float wave_reduce(float v) {
#pragma unroll
    for (int off = 32; off > 0; off >>= 1)
        v += __shfl_down(v, off, 64);
    return v;
}

// ---- Fused: BCE sum + channel-0 count + channel-1 dense segment monoid ----
// Block geometry: blockIdx covers float4 [bi*3072, bi*3072+3072) =
// rows [48s, 48s+48) of slab (b= bi>>3, c=(bi>>2)&1), s = bi&3.
// For c==1 blocks, 4 ballots per row pack the (p>0.5) mask into LDS
// (48 rows x 4 uint64 = 1.5 KB); after the barrier each thread owns one
// column and computes the (first,last,sum) monoid from its 48-bit mask.
// Dense data is thus consumed from the loads bce already does — the 48 MB
// dense re-read of R6 is eliminated.
__global__ __launch_bounds__(256, 8) void bce_cuts_dense_kernel(
        const vfloat4* __restrict__ p4,
        const vfloat4* __restrict__ t4,
        float2* __restrict__ part,
        float* __restrict__ segsum,
        short* __restrict__ segfirst,
        short* __restrict__ seglast) {
    const int bi   = blockIdx.x;
    const int base = bi * (256 * PAIRS) + threadIdx.x;
    const int c    = (bi >> 2) & 1;   // channel of this block (uniform)
    const int s    = bi & 3;          // row-segment index, rows [48s,48s+48)
    const int bb   = bi >> 3;         // batch
    const int lane = threadIdx.x & 63;
    const int wid  = threadIdx.x >> 6;

    __shared__ unsigned long long rm[48][4];  // [local row][e] ballot masks
    __shared__ float sb[4], sc[4];

    float bce  = 0.0f;
    float cuts = 0.0f;

    vfloat4 pc = nt_load4(&p4[base]);
    vfloat4 tc = nt_load4(&t4[base]);

#pragma unroll
    for (int k = 0; k < PAIRS; ++k) {
        vfloat4 pn, tn;
        if (k + 1 < PAIRS) {
            pn = nt_load4(&p4[base + (k + 1) * 256]);
            tn = nt_load4(&t4[base + (k + 1) * 256]);
        }

        bool gt[4];
#pragma unroll
        for (int e = 0; e < 4; ++e) {
            const float pv = pc[e];
            const float tv = tc[e];
            const float lp = fast_log(pv);
            const float lm = fast_log(1.0f - pv);
            bce += lm + tv * (lp - lm);   // == t*lp + (1-t)*lm
            gt[e] = pv > THRESH;
        }

        if (c == 0) {
            cuts += (gt[0] ? 1.0f : 0.0f) + (gt[1] ? 1.0f : 0.0f)
                  + (gt[2] ? 1.0f : 0.0f) + (gt[3] ? 1.0f : 0.0f);
        } else {
            // Wave covers one full row: lane l holds columns 4l..4l+3.
            // Row = 48s + 4k + wid (unique per (k,wid), covers 0..47).
            const unsigned long long m0 = __ballot(gt[0]);
            const unsigned long long m1 = __ballot(gt[1]);
            const unsigned long long m2 = __ballot(gt[2]);
            const unsigned long long m3 = __ballot(gt[3]);
            if (lane == 0) {
                const int lr = 4 * k + wid;
                rm[lr][0] = m0; rm[lr][1] = m1;
                rm[lr][2] = m2; rm[lr][3] = m3;
            }
        }

        pc = pn;
        tc = tn;
    }

    float rb = wave_reduce(bce);
    float rc = wave_reduce(cuts);
    if (lane == 0) { sb[wid] = rb; sc[wid] = rc; }
    __syncthreads();   // orders rm[] writes AND sb/sc writes

    if (threadIdx.x == 0)
        part[bi] = make_float2(sb[0] + sb[1] + sb[2] + sb[3],
                               sc[0] + sc[1] + sc[2] + sc[3]);

    if (c == 1) {
        // Thread owns column w. Bit for column w of row lr lives in
        // rm[lr][w&3] at bit position (w>>2).
        const int w = threadIdx.x;
        const int e = w & 3;
        const int l = w >> 2;
        unsigned long long cm = 0ull;
#pragma unroll
        for (int lr = 0; lr < 48; ++lr)
            cm |= ((rm[lr][e] >> l) & 1ull) << lr;
        // Reference semantics: row-0 hits are no-ops (prev sentinel 0),
        // row 191 never scanned (arange(H-1)).
        if (s == 0) cm &= ~1ull;
        if (s == 3) cm &= ~(1ull << 47);

        short first = -1, last = -1;
        float sum = 0.0f;
        if (cm) {
            int i = __builtin_ctzll(cm);
            first = (short)(48 * s + i);
            unsigned long long m = cm & (cm - 1);
            int prev = i;
            while (m) {
                const int jj = __builtin_ctzll(m);
                const float d = (float)(jj - prev);
                sum += __builtin_amdgcn_rcpf(d * d * d);
                prev = jj;
                m &= m - 1;
            }
            last = (short)(48 * s + prev);
        }
        const int j = bb * 256 + w;          // global column id
        segsum  [s * NCOL + j] = sum;
        segfirst[s * NCOL + j] = first;
        seglast [s * NCOL + j] = last;
    }
}

// ---- merge 4 row-segments per column (2 MB read vs R6's 48 MB) ----
__global__ __launch_bounds__(256) void dense_merge_kernel(
        const float* __restrict__ segsum,
        const short* __restrict__ segfirst,
        const short* __restrict__ seglast,
        float* __restrict__ part) {
    const int j = blockIdx.x * 256 + threadIdx.x;  // column 0..65535
    int   mlast = -1;
    float msum  = 0.0f;
#pragma unroll
    for (int s = 0; s < 4; ++s) {
        const int f = segfirst[s * NCOL + j];
        if (f >= 0) {
            if (mlast >= 0) {
                const float d = (float)(f - mlast);
                msum += __builtin_amdgcn_rcpf(d * d * d);
            }
            msum += segsum[s * NCOL + j];
            mlast = seglast[s * NCOL + j];
        }
    }
    float r = wave_reduce(msum);
    __shared__ float sd[4];
    const int lane = threadIdx.x & 63;
    const int wid  = threadIdx.x >> 6;
    if (lane == 0) sd[wid] = r;
    __syncthreads();
    if (threadIdx.x == 0)
        part[blockIdx.x] = sd[0] + sd[1] + sd[2] + sd[3];
}

// ---- single-block reduction of all partials + final combine ----
__global__ __launch_bounds__(256) void finalize_kernel(
        const float2* __restrict__ part_bce,
        const float* __restrict__ part_dense,
        float* __restrict__ out) {
    float b = 0.0f, c = 0.0f, d = 0.0f;
    for (int i = threadIdx.x; i < BCE_BLOCKS; i += 256) {
        float2 v = part_bce[i];
        b += v.x;
        c += v.y;
    }
    for (int i = threadIdx.x; i < MERGE_BLOCKS; i += 256)
        d += part_dense[i];

    __shared__ float sb[4], sc[4], sd[4];
    float rb = wave_reduce(b);
    float rc = wave_reduce(c);
    float rd = wave_reduce(d);
    const int lane = threadIdx.x & 63;
    const int wid  = threadIdx.x >> 6;
    if (lane == 0) { sb[wid] = rb; sc[wid] = rc; sd[wid] = rd; }
    __syncthreads();
    if (threadIdx.x == 0) {
        const float bce_sum   = sb[0] + sb[1] + sb[2] + sb[3];
        const float cuts_sum  = sc[0] + sc[1] + sc[2] + sc[3];
        const float dense_sum = sd[0] + sd[1] + sd[2] + sd[3];
        const float bce = -bce_sum / (float)NTOT;
        out[0] = ALPHA * bce + BETA * cuts_sum + GAMMA * dense_sum;
    }
}

extern "C" void kernel_launch(void* const* d_in, const int* in_sizes, int n_in,
                              void* d_out, int out_size, void* d_ws, size_t ws_size,
                              hipStream_t stream) {
    const float* inputs  = (const float*)d_in[0];
    const float* targets = (const float*)d_in[1];
    float* out = (float*)d_out;

    // ws layout (all offsets 4-byte aligned):
    //   float2 part_bce[2048]          : 16 KB
    //   float  segsum  [4*65536]       : 1 MB
    //   short  segfirst[4*65536]       : 512 KB
    //   short  seglast [4*65536]       : 512 KB
    //   float  part_dense[256]
    float2* part_bce = (float2*)d_ws;
    char*   p        = (char*)d_ws + BCE_BLOCKS * sizeof(float2);
    float*  segsum   = (float*)p;  p += 4 * NCOL * sizeof(float);
    short*  segfirst = (short*)p;  p += 4 * NCOL * sizeof(short);
    short*  seglast  = (short*)p;  p += 4 * NCOL * sizeof(short);
    float*  part_dense = (float*)p;

    bce_cuts_dense_kernel<<<BCE_BLOCKS, 256, 0, stream>>>(
        (const vfloat4*)inputs, (const vfloat4*)targets,
        part_bce, segsum, segfirst, seglast);

    dense_merge_kernel<<<MERGE_BLOCKS, 256, 0, stream>>>(
        segsum, segfirst, seglast, part_dense);

    finalize_kernel<<<1, 256, 0, stream>>>(part_bce, part_dense, out);
}

// Round 8
// 209.898 us; speedup vs baseline: 1.1256x; 1.1256x over previous
//
#include <hip/hip_runtime.h>
#include <math.h>

// Problem constants (match reference)
#define ALPHA     1.0f
#define BETA      0.001f
#define GAMMA     0.1f
#define THRESH    0.5f
#define LOG_CLAMP -100.0f
#define LN2       0.69314718055994530942f

constexpr int B = 256, C = 2, H = 192, W = 256;
constexpr int HW   = H * W;          // 49152
constexpr int HW4  = HW / 4;         // 12288 float4 per (b,c) slab
constexpr long long NTOT = (long long)B * C * H * W;  // 25165824
constexpr int N4   = (int)(NTOT / 4);                  // 6291456

constexpr int BCE_BLOCKS   = 2048;   // 8 blocks/CU exact fill (32 waves/CU)
constexpr int PAIRS        = 12;     // 2048*256*12 == N4 exactly
constexpr int BATCH        = 6;      // loads kept in flight per batch
constexpr int DENSE_BLOCKS = 1024;

// Native Clang vector type — __builtin_nontemporal_load rejects HIP's float4.
typedef float vfloat4 __attribute__((ext_vector_type(4)));

// Hardware v_log_f32 (log2) * ln2, ~1 ulp — threshold is 6.7e3 absolute.
__device__ __forceinline__ float fast_log(float x) {
    return fmaxf(__builtin_amdgcn_logf(x) * LN2, LOG_CLAMP);
}

__device__ __forceinline__ vfloat4 nt_load4(const vfloat4* p) {
    return __builtin_nontemporal_load(p);
}

__device__ __forceinline__ float wave_reduce(float v) {
#pragma unroll
    for (int off = 32; off > 0; off >>= 1)
        v += __shfl_down(v, off, 64);
    return v;
}

// ---- BCE sum + channel-0 count(>0.5) ----
// R7 fusion regressed -> reverted to the R6 standalone form.  Change vs R6:
// batches of 6 pairs (12 nt loads issued back-to-back, 48 VGPRs of data)
// under a (256,8) = 64-VGPR budget, so the allocator keeps them in flight.
// R4 evidence: this pattern is concurrency-limited (duration invariant to
// HBM-vs-L3 source); every added-concurrency step has paid so far.
__global__ __launch_bounds__(256, 8) void bce_cuts_kernel(
        const vfloat4* __restrict__ p4,
        const vfloat4* __restrict__ t4,
        float2* __restrict__ part) {
    const int base = blockIdx.x * (256 * PAIRS) + threadIdx.x;

    float bce  = 0.0f;
    float cuts = 0.0f;

#pragma unroll
    for (int kb = 0; kb < PAIRS; kb += BATCH) {
        vfloat4 p[BATCH], t[BATCH];
#pragma unroll
        for (int u = 0; u < BATCH; ++u) {
            p[u] = nt_load4(&p4[base + (kb + u) * 256]);
            t[u] = nt_load4(&t4[base + (kb + u) * 256]);
        }
#pragma unroll
        for (int u = 0; u < BATCH; ++u) {
            const int f = base + (kb + u) * 256;
            const int c = (f / HW4) & 1;   // channel of this float4
#pragma unroll
            for (int e = 0; e < 4; ++e) {
                const float pv = p[u][e];
                const float tv = t[u][e];
                const float lp = fast_log(pv);
                const float lm = fast_log(1.0f - pv);
                bce += lm + tv * (lp - lm);   // == t*lp + (1-t)*lm
                if (c == 0)
                    cuts += (pv > THRESH ? 1.0f : 0.0f);
            }
        }
    }

    __shared__ float sb[4], sc[4];
    float rb = wave_reduce(bce);
    float rc = wave_reduce(cuts);
    const int lane = threadIdx.x & 63;
    const int wid  = threadIdx.x >> 6;
    if (lane == 0) { sb[wid] = rb; sc[wid] = rc; }
    __syncthreads();
    if (threadIdx.x == 0) {
        part[blockIdx.x] = make_float2(sb[0] + sb[1] + sb[2] + sb[3],
                                       sc[0] + sc[1] + sc[2] + sc[3]);
    }
}

// ---- dense penalty, segmented scan (R6 structure) ----
// Hits in rows [1..190] of channel 1; consecutive hits (i,j) add 1/(j-i)^3.
// Column split into 4 row-segments (4 waves/block), merged via the
// associative (first, last, sum) monoid in LDS.
// Change vs R6: (256,4) launch bounds (128-VGPR budget) so the 48-row
// register prefetch is not serialized by the allocator.
__global__ __launch_bounds__(256, 4) void dense_kernel(
        const float* __restrict__ in,
        float* __restrict__ part) {
    const int lane = threadIdx.x & 63;
    const int seg  = threadIdx.x >> 6;            // 0..3, rows [seg*48, seg*48+48)
    const int j    = blockIdx.x * 64 + lane;      // column id, 0..65535
    const int b    = j >> 8;                      // W == 256
    const int w    = j & 255;
    const float* col = in + ((b * 2 + 1) * H) * W + w;  // channel 1 of batch b
    const int segbase = seg * 48;

    float v[48];
#pragma unroll
    for (int k = 0; k < 48; ++k)
        v[k] = col[(segbase + k) * W];

    int   first = -1, last = -1;
    float sum = 0.0f;
#pragma unroll
    for (int k = 0; k < 48; ++k) {
        const int i = segbase + k;
        const bool m = (v[k] > THRESH) && (i != 0) && (i != 191);
        if (m) {
            if (last >= 0) {
                const float d = (float)(i - last);
                sum += __builtin_amdgcn_rcpf(d * d * d);
            } else {
                first = i;
            }
            last = i;
        }
    }

    __shared__ int   sfirst[256];
    __shared__ int   slast[256];
    __shared__ float ssum[256];
    sfirst[threadIdx.x] = first;
    slast[threadIdx.x]  = last;
    ssum[threadIdx.x]   = sum;
    __syncthreads();

    if (threadIdx.x < 64) {  // wave 0 merges the 4 segments of its column
        int   mlast = -1;
        float msum  = 0.0f;
#pragma unroll
        for (int s = 0; s < 4; ++s) {
            const int idx = s * 64 + threadIdx.x;
            const int f = sfirst[idx];
            if (f >= 0) {
                if (mlast >= 0) {
                    const float d = (float)(f - mlast);
                    msum += __builtin_amdgcn_rcpf(d * d * d);
                }
                msum += ssum[idx];
                mlast = slast[idx];
            }
        }
        float r = wave_reduce(msum);
        if (threadIdx.x == 0)
            part[blockIdx.x] = r;
    }
}

// ---- single-block reduction of all partials + final combine ----
__global__ __launch_bounds__(256) void finalize_kernel(
        const float2* __restrict__ part_bce,
        const float* __restrict__ part_dense,
        float* __restrict__ out) {
    float b = 0.0f, c = 0.0f, d = 0.0f;
    for (int i = threadIdx.x; i < BCE_BLOCKS; i += 256) {
        float2 v = part_bce[i];
        b += v.x;
        c += v.y;
    }
    for (int i = threadIdx.x; i < DENSE_BLOCKS; i += 256)
        d += part_dense[i];

    __shared__ float sb[4], sc[4], sd[4];
    float rb = wave_reduce(b);
    float rc = wave_reduce(c);
    float rd = wave_reduce(d);
    const int lane = threadIdx.x & 63;
    const int wid  = threadIdx.x >> 6;
    if (lane == 0) { sb[wid] = rb; sc[wid] = rc; sd[wid] = rd; }
    __syncthreads();
    if (threadIdx.x == 0) {
        const float bce_sum   = sb[0] + sb[1] + sb[2] + sb[3];
        const float cuts_sum  = sc[0] + sc[1] + sc[2] + sc[3];
        const float dense_sum = sd[0] + sd[1] + sd[2] + sd[3];
        const float bce = -bce_sum / (float)NTOT;
        out[0] = ALPHA * bce + BETA * cuts_sum + GAMMA * dense_sum;
    }
}

extern "C" void kernel_launch(void* const* d_in, const int* in_sizes, int n_in,
                              void* d_out, int out_size, void* d_ws, size_t ws_size,
                              hipStream_t stream) {
    const float* inputs  = (const float*)d_in[0];
    const float* targets = (const float*)d_in[1];
    float* out = (float*)d_out;

    // ws layout: [0 .. BCE_BLOCKS)  float2 bce partials
    //            then DENSE_BLOCKS float dense partials
    float2* part_bce   = (float2*)d_ws;
    float*  part_dense = (float*)d_ws + 2 * BCE_BLOCKS;

    bce_cuts_kernel<<<BCE_BLOCKS, 256, 0, stream>>>(
        (const vfloat4*)inputs, (const vfloat4*)targets, part_bce);

    dense_kernel<<<DENSE_BLOCKS, 256, 0, stream>>>(inputs, part_dense);

    finalize_kernel<<<1, 256, 0, stream>>>(part_bce, part_dense, out);
}